// Round 11
// baseline (205.154 us; speedup 1.0000x reference)
//
#include <hip/hip_runtime.h>

#define N_EDGES_C 1048576

typedef __attribute__((ext_vector_type(8))) __bf16 bf16x8;
typedef __attribute__((ext_vector_type(4))) __bf16 bf16x4;
typedef __attribute__((ext_vector_type(4))) float f32x4;

#define MFMA16(a,b,c) __builtin_amdgcn_mfma_f32_16x16x32_bf16((a),(b),(c),0,0,0)

// LDS-visible barrier that does NOT drain vmcnt.
#define BARRIER() do { asm volatile("s_waitcnt lgkmcnt(0)" ::: "memory"); \
                       __builtin_amdgcn_s_barrier(); \
                       asm volatile("" ::: "memory"); } while (0)

__device__ __forceinline__ unsigned short f2bf(float f) {
  unsigned int u = __builtin_bit_cast(unsigned int, f);
  u = (u + 0x7fffu + ((u >> 16) & 1u)) >> 16;
  return (unsigned short)u;
}
__device__ __forceinline__ float bf2f(unsigned short h) {
  unsigned int u = ((unsigned int)h) << 16;
  return __builtin_bit_cast(float, u);
}

// ---------------- prep ----------------
__global__ void prep_kernel(const float* __restrict__ Wc0s, const float* __restrict__ Wc0n,
                            const float* __restrict__ Wc1s, const float* __restrict__ Wc1n,
                            const float* __restrict__ Wa,
                            const float* __restrict__ bc0, const float* __restrict__ g0,
                            const float* __restrict__ b0, const float* __restrict__ m0,
                            const float* __restrict__ v0,
                            const float* __restrict__ bc1, const float* __restrict__ g1,
                            const float* __restrict__ b1, const float* __restrict__ m1,
                            const float* __restrict__ v1,
                            const float* __restrict__ Wr0, const float* __restrict__ Wr1,
                            unsigned short* __restrict__ wbf, float* __restrict__ cst,
                            float* __restrict__ wr0t, float* __restrict__ wr1t) {
  int t = blockIdx.x * blockDim.x + threadIdx.x;
  if (t < 8192) {
    int d = t >> 6, f = t & 63;
    wbf[t]        = f2bf(Wc0s[f * 128 + d]);
    wbf[8192 + t] = f2bf(Wc0n[f * 128 + d]);
  } else if (t < 24576) {
    int i = t - 8192;
    int d = i >> 7, k = i & 127;
    wbf[16384 + i] = f2bf(Wc1s[k * 128 + d]);
    wbf[32768 + i] = f2bf(Wc1n[k * 128 + d]);
    wbf[49152 + i] = f2bf(Wa[k * 128 + d]);
  } else if (t < 24704) {
    int d = t - 24576;
    float s0 = g0[d] * rsqrtf(v0[d] + 1e-5f);
    cst[d]       = s0;
    cst[128 + d] = (bc0[d] - m0[d]) * s0 + b0[d];
    float s1 = g1[d] * rsqrtf(v1[d] + 1e-5f);
    cst[256 + d] = s1;
    cst[384 + d] = (bc1[d] - m1[d]) * s1 + b1[d];
  } else if (t < 57472) {
    int i = t - 24704;
    int which = i >> 14;
    int k = i & 16383;
    int d = k >> 7, j = k & 127;
    float v = (which ? Wr1 : Wr0)[j * 128 + d];
    (which ? wr1t : wr0t)[k] = v;
  }
}

// ---------------- megakernel: 1 block = 1 graph, 80KB arena, 2/CU, 11 barriers ----------------
__global__ __launch_bounds__(512, 4)
void gnn_fused(const float* __restrict__ x, const float* __restrict__ mwt,
               const int* __restrict__ ei,
               const unsigned short* __restrict__ wbf, const float* __restrict__ cst,
               const float* __restrict__ ba,
               float* __restrict__ pooled) {
  __shared__ __align__(16) unsigned char arena[81920];
  unsigned short* S0  = (unsigned short*)(arena);            // V0h0 -> h1h0 -> p_h0
  unsigned short* S1  = (unsigned short*)(arena + 16384);    // V0h1 -> h1h1 -> p_h1
  unsigned short* S2  = (unsigned short*)(arena + 32768);    // deg -> V1h0 -> h2h0
  unsigned char*  CNT = arena + 49152;                       // counts -> pool/sv1
  unsigned short* S4  = (unsigned short*)(arena + 65536);    // x -> V1h1 -> h2h1
  float* S2f = (float*)S2;
  float* S3f = (float*)CNT;

  const int gb = blockIdx.x;
  const int t = threadIdx.x;
  const int lane = t & 63;
  const int w = t >> 6;
  const int c  = lane & 15;
  const int gq = lane >> 4;
  const int r0 = gq << 2;
  const int mt = w >> 2;        // d-tile 0..1
  const int nn = w & 3;         // node-tile 0..3
  const f32x4 zero = {0.f, 0.f, 0.f, 0.f};

  auto lk = [](float v) { return v > 0.f ? v : 0.01f * v; };
  auto ldH = [&](const unsigned short* H, int nodeB, int kl) -> bf16x8 {
    int r = nodeB + c;
    int cb2 = (kl + gq * 8) * 2;
    return *(const bf16x8*)((const char*)H + r * 128 + (cb2 ^ ((r & 7) << 4)));
  };
  auto ldV = [&](const unsigned short* V, int dB, int nodek) -> bf16x8 {
    int r = dB + c;
    int cb2 = (nodek + gq * 8) * 2;
    return *(const bf16x8*)((const char*)V + r * 256 + (cb2 ^ ((r & 7) << 4)));
  };
  // self-contained 32-K GEMM chunk: acc += W[dd..dd+32][kb..kb+32] @ H[ntile][kl..kl+32]
  auto gemmChunk = [&](const unsigned short* Wt, int K, int dd, int kb,
                       const unsigned short* H, int kl, f32x4* a4) {
    bf16x8 a0 = *(const bf16x8*)(Wt + (dd + c) * K + kb + gq * 8);
    bf16x8 a1 = *(const bf16x8*)(Wt + (dd + 16 + c) * K + kb + gq * 8);
    bf16x8 b0 = ldH(H, nn * 32, kl);
    bf16x8 b1 = ldH(H, nn * 32 + 16, kl);
    a4[0] = MFMA16(a0, b0, a4[0]);
    a4[1] = MFMA16(a0, b1, a4[1]);
    a4[2] = MFMA16(a1, b0, a4[2]);
    a4[3] = MFMA16(a1, b1, a4[3]);
  };

  // ==== P0: load edges; zero counts + deg; x -> S4 ====
  int els, eld;
  {
    int e = gb * 512 + t;
    els = ei[e] & 127;
    eld = ei[N_EDGES_C + e] & 127;
  }
  {
    unsigned int* c32 = (unsigned int*)CNT;
    for (int i = t; i < 4096; i += 512) c32[i] = 0u;
    if (t < 128) S2f[t] = 0.f;
  }
  {
    const float4* xg = (const float4*)(x + (size_t)gb * 8192);
#pragma unroll
    for (int i = 0; i < 4; i++) {
      int vi = t + i * 512;
      float4 v = xg[vi];
      int node = vi >> 4;
      int f2 = (vi & 15) * 8;
      bf16x4 qv = {(__bf16)v.x, (__bf16)v.y, (__bf16)v.z, (__bf16)v.w};
      *(bf16x4*)((char*)S4 + node * 128 + (f2 ^ ((node & 7) << 4))) = qv;
    }
  }
  BARRIER();

  // ==== P1: histogram counts[dst][src] + deg[dst] ====
  {
    int cb = els ^ ((eld & 7) << 3);
    int idx = eld * 128 + cb;
    atomicAdd((unsigned int*)(CNT + (idx & ~3)), 1u << ((idx & 3) * 8));
    atomicAdd(&S2f[eld], 1.f);
  }
  BARRIER();

  const float inv0 = 1.f / fmaxf(S2f[nn * 32 + c], 1.f);
  const float inv1 = 1.f / fmaxf(S2f[nn * 32 + 16 + c], 1.f);

  auto ldAdj = [&](int noBase, int kb, float inv) -> bf16x8 {
    int m = noBase + c;
    int cc = (kb + gq * 8) ^ ((m & 7) << 3);
    const unsigned int* p = (const unsigned int*)(CNT + m * 128 + cc);
    unsigned int w0 = p[0], w1 = p[1];
    bf16x8 r;
#pragma unroll
    for (int i2 = 0; i2 < 4; i2++) {
      r[i2]     = (__bf16)((float)((w0 >> (8 * i2)) & 0xffu) * inv);
      r[4 + i2] = (__bf16)((float)((w1 >> (8 * i2)) & 0xffu) * inv);
    }
    return r;
  };
  auto gemmA = [&](const unsigned short* V, f32x4* a4, int kb) {
    bf16x8 A0 = ldV(V, mt * 32, kb);
    bf16x8 A1 = ldV(V, mt * 32 + 16, kb);
    bf16x8 B0 = ldAdj(nn * 32, kb, inv0);
    bf16x8 B1 = ldAdj(nn * 32 + 16, kb, inv1);
    a4[0] = MFMA16(A0, B0, a4[0]);
    a4[1] = MFMA16(A0, B1, a4[1]);
    a4[2] = MFMA16(A1, B0, a4[2]);
    a4[3] = MFMA16(A1, B1, a4[3]);
  };
  auto epiV = [&](unsigned short* V, f32x4* av) {
#pragma unroll
    for (int i = 0; i < 2; i++)
#pragma unroll
      for (int n = 0; n < 2; n++) {
        f32x4 v = av[i * 2 + n];
        float a0 = v[0], a1 = v[1], a2 = v[2], a3 = v[3];
        {
          bool lo = (lane & 1) == 0;
          float sA = lo ? a1 : a0, sB = lo ? a3 : a2;
          float rA = __shfl_xor(sA, 1), rB = __shfl_xor(sB, 1);
          if (lo) { a1 = rA; a3 = rB; } else { a0 = rA; a2 = rB; }
        }
        {
          bool lo = (lane & 2) == 0;
          float sA = lo ? a2 : a0, sB = lo ? a3 : a1;
          float rA = __shfl_xor(sA, 2), rB = __shfl_xor(sB, 2);
          if (lo) { a2 = rA; a3 = rB; } else { a0 = rA; a1 = rB; }
        }
        int dloc = mt * 32 + 16 * i + r0 + (lane & 3);
        int nodeB2 = (nn * 32 + 16 * n + ((lane >> 2) & 3) * 4) * 2;
        bf16x4 o = {(__bf16)a0, (__bf16)a1, (__bf16)a2, (__bf16)a3};
        *(bf16x4*)((char*)V + dloc * 256 + (nodeB2 ^ ((dloc & 7) << 4))) = o;
      }
  };
  auto epiF = [&](unsigned short* H, f32x4* A, const float* mul0, const float* add0,
                  bool bn, float mwa, float mwb) {
#pragma unroll
    for (int i = 0; i < 2; i++) {
      int dB = mt * 32 + 16 * i + r0;
      float4 mul4 = bn ? *(const float4*)(mul0 + dB) : float4{0, 0, 0, 0};
      float4 add4 = *(const float4*)(add0 + dB);
#pragma unroll
      for (int n = 0; n < 2; n++) {
        f32x4 v = A[i * 2 + n];
        float mw = n ? mwb : mwa;
        int node = nn * 32 + 16 * n + c;
        bf16x4 o;
        if (bn) {
          o = bf16x4{(__bf16)(lk(v[0] * mul4.x + add4.x) * mw),
                     (__bf16)(lk(v[1] * mul4.y + add4.y) * mw),
                     (__bf16)(lk(v[2] * mul4.z + add4.z) * mw),
                     (__bf16)(lk(v[3] * mul4.w + add4.w) * mw)};
        } else {
          o = bf16x4{(__bf16)lk(v[0] + add4.x), (__bf16)lk(v[1] + add4.y),
                     (__bf16)lk(v[2] + add4.z), (__bf16)lk(v[3] + add4.w)};
        }
        *(bf16x4*)((char*)H + node * 128 + ((2 * dB) ^ ((node & 7) << 4))) = o;
      }
    }
  };

  f32x4 va[4], ca[4], cb4[4];

  // ==== P3: V0 = W0n@x (half at a time, single acc); epiV -> S0,S1 ====
#pragma unroll
  for (int i = 0; i < 4; i++) va[i] = zero;
  gemmChunk(wbf + 8192, 64, mt * 32, 0, S4, 0, va);
  gemmChunk(wbf + 8192, 64, mt * 32, 32, S4, 32, va);
  epiV(S0, va);
#pragma unroll
  for (int i = 0; i < 4; i++) va[i] = zero;
  gemmChunk(wbf + 8192, 64, 64 + mt * 32, 0, S4, 0, va);
  gemmChunk(wbf + 8192, 64, 64 + mt * 32, 32, S4, 32, va);
  epiV(S1, va);
  BARRIER();

  // ==== P4: conv0 = Adj@V0 (first) + W0s@x (both halves) ====
#pragma unroll
  for (int i = 0; i < 4; i++) { ca[i] = zero; cb4[i] = zero; }
  for (int kb = 0; kb < 128; kb += 32) {
    gemmA(S0, ca, kb);
    gemmA(S1, cb4, kb);
  }
  gemmChunk(wbf, 64, mt * 32, 0, S4, 0, ca);
  gemmChunk(wbf, 64, mt * 32, 32, S4, 32, ca);
  gemmChunk(wbf, 64, 64 + mt * 32, 0, S4, 0, cb4);
  gemmChunk(wbf, 64, 64 + mt * 32, 32, S4, 32, cb4);
  BARRIER();

  // ==== P5: BN0 epi -> h1 (S0,S1) ====
  epiF(S0, ca, cst, cst + 128, true, 1.f, 1.f);
  epiF(S1, cb4, cst + 64, cst + 192, true, 1.f, 1.f);
  BARRIER();

  // ==== P6: V1 = W1n@h1 (K=128, half at a time); epiV -> S2,S4 ====
#pragma unroll
  for (int i = 0; i < 4; i++) va[i] = zero;
  gemmChunk(wbf + 32768, 128, mt * 32, 0, S0, 0, va);
  gemmChunk(wbf + 32768, 128, mt * 32, 32, S0, 32, va);
  gemmChunk(wbf + 32768, 128, mt * 32, 64, S1, 0, va);
  gemmChunk(wbf + 32768, 128, mt * 32, 96, S1, 32, va);
  epiV(S2, va);
#pragma unroll
  for (int i = 0; i < 4; i++) va[i] = zero;
  gemmChunk(wbf + 32768, 128, 64 + mt * 32, 0, S0, 0, va);
  gemmChunk(wbf + 32768, 128, 64 + mt * 32, 32, S0, 32, va);
  gemmChunk(wbf + 32768, 128, 64 + mt * 32, 64, S1, 0, va);
  gemmChunk(wbf + 32768, 128, 64 + mt * 32, 96, S1, 32, va);
  epiV(S4, va);
  BARRIER();

  // ==== P7: conv1 = Adj@V1 (first) + W1s@h1 (both halves) ====
#pragma unroll
  for (int i = 0; i < 4; i++) { ca[i] = zero; cb4[i] = zero; }
  for (int kb = 0; kb < 128; kb += 32) {
    gemmA(S2, ca, kb);
    gemmA(S4, cb4, kb);
  }
  gemmChunk(wbf + 16384, 128, mt * 32, 0, S0, 0, ca);
  gemmChunk(wbf + 16384, 128, mt * 32, 32, S0, 32, ca);
  gemmChunk(wbf + 16384, 128, mt * 32, 64, S1, 0, ca);
  gemmChunk(wbf + 16384, 128, mt * 32, 96, S1, 32, ca);
  gemmChunk(wbf + 16384, 128, 64 + mt * 32, 0, S0, 0, cb4);
  gemmChunk(wbf + 16384, 128, 64 + mt * 32, 32, S0, 32, cb4);
  gemmChunk(wbf + 16384, 128, 64 + mt * 32, 64, S1, 0, cb4);
  gemmChunk(wbf + 16384, 128, 64 + mt * 32, 96, S1, 32, cb4);
  float mw0 = mwt[(size_t)gb * 128 + nn * 32 + c];
  float mw1 = mwt[(size_t)gb * 128 + nn * 32 + 16 + c];
  BARRIER();

  // ==== P8: BN1+mw epi -> h2 (S2,S4); zero S3f (counts dead) ====
  epiF(S2, ca, cst + 256, cst + 384, true, mw0, mw1);
  epiF(S4, cb4, cst + 320, cst + 448, true, mw0, mw1);
  if (t < 256) S3f[t] = 0.f;
  BARRIER();

  // ==== P9: p = Wa@h2 (half at a time); +ba leaky epi -> S0,S1 (h1 dead) ====
#pragma unroll
  for (int i = 0; i < 4; i++) va[i] = zero;
  gemmChunk(wbf + 49152, 128, mt * 32, 0, S2, 0, va);
  gemmChunk(wbf + 49152, 128, mt * 32, 32, S2, 32, va);
  gemmChunk(wbf + 49152, 128, mt * 32, 64, S4, 0, va);
  gemmChunk(wbf + 49152, 128, mt * 32, 96, S4, 32, va);
  epiF(S0, va, nullptr, ba, false, 1.f, 1.f);
#pragma unroll
  for (int i = 0; i < 4; i++) va[i] = zero;
  gemmChunk(wbf + 49152, 128, 64 + mt * 32, 0, S2, 0, va);
  gemmChunk(wbf + 49152, 128, 64 + mt * 32, 32, S2, 32, va);
  gemmChunk(wbf + 49152, 128, 64 + mt * 32, 64, S4, 0, va);
  gemmChunk(wbf + 49152, 128, 64 + mt * 32, 96, S4, 32, va);
  epiF(S1, va, nullptr, ba + 64, false, 1.f, 1.f);
  BARRIER();

  // ==== P10: pair = sigmoid(pA@pB^T) -> row/col sums (sv1 @ S3f+128) ====
  {
    f32x4 acc2[2] = {zero, zero};
    for (int kb = 0; kb < 128; kb += 32) {
      const unsigned short* H = (kb < 64) ? S0 : S1;
      int kl = kb & 63;
#pragma unroll
      for (int i = 0; i < 2; i++) {
        int T = w * 2 + i;
        bf16x8 a = ldH(H, (T >> 2) * 16, kl);
        bf16x8 b = ldH(H, 64 + (T & 3) * 16, kl);
        acc2[i] = MFMA16(a, b, acc2[i]);
      }
    }
    float* sv1 = S3f + 128;
#pragma unroll
    for (int i = 0; i < 2; i++) {
      int T = w * 2 + i, mb = (T >> 2) * 16, nb = (T & 3) * 16;
      float s0 = 1.f / (1.f + __expf(-acc2[i][0]));
      float s1 = 1.f / (1.f + __expf(-acc2[i][1]));
      float s2 = 1.f / (1.f + __expf(-acc2[i][2]));
      float s3 = 1.f / (1.f + __expf(-acc2[i][3]));
      atomicAdd(&sv1[64 + nb + c], s0 + s1 + s2 + s3);
#pragma unroll
      for (int m = 1; m < 16; m <<= 1) {
        s0 += __shfl_xor(s0, m); s1 += __shfl_xor(s1, m);
        s2 += __shfl_xor(s2, m); s3 += __shfl_xor(s3, m);
      }
      if (c < 4) {
        float v = c == 0 ? s0 : (c == 1 ? s1 : (c == 2 ? s2 : s3));
        atomicAdd(&sv1[mb + r0 + c], v);
      }
    }
  }
  BARRIER();

  // ==== P11: pool[d] = sum_node (u[node]*p[node][d] + h2[node][d]) ====
  {
    int d = t & 127, qd = t >> 7;
    const unsigned short* Hp = (d < 64) ? S0 : S1;
    const unsigned short* Hh = (d < 64) ? S2 : S4;
    int dl2 = (d & 63) * 2;
    float s = 0.f;
#pragma unroll
    for (int i = 0; i < 32; i++) {
      int node = qd * 32 + i;
      float u = S3f[128 + node];
      int off = dl2 ^ ((node & 7) << 4);
      float pv = bf2f(*(const unsigned short*)((const char*)Hp + node * 128 + off));
      float hv = bf2f(*(const unsigned short*)((const char*)Hh + node * 128 + off));
      s += u * pv + hv;
    }
    atomicAdd(&S3f[d], s);
  }
  BARRIER();

  // ==== P12: write pooled mean ====
  if (t < 128) pooled[(size_t)gb * 128 + t] = S3f[t] * (1.f / 128.f);
}

// ---------------- readout ----------------
__global__ __launch_bounds__(128)
void readout_kernel(const float* __restrict__ pooled,
                    const float* __restrict__ wr0t, const float* __restrict__ br0,
                    const float* __restrict__ wr1t, const float* __restrict__ br1,
                    const float* __restrict__ Wout, const float* __restrict__ bout,
                    float* __restrict__ out) {
  __shared__ float pl[128], t1[128];
  __shared__ float sred[2];
  int g = blockIdx.x, t = threadIdx.x;
  pl[t] = pooled[(size_t)g * 128 + t];
  __syncthreads();
  {
    const float* row = wr0t + t * 128;
    float s = 0.f;
#pragma unroll 8
    for (int j = 0; j < 128; j++) s += pl[j] * row[j];
    s += br0[t];
    t1[t] = s > 0.f ? s : 0.01f * s;
  }
  __syncthreads();
  float v2;
  {
    const float* row = wr1t + t * 128;
    float s = 0.f;
#pragma unroll 8
    for (int j = 0; j < 128; j++) s += t1[j] * row[j];
    s += br1[t];
    s = s > 0.f ? s : 0.01f * s;
    v2 = s * Wout[t];
  }
#pragma unroll
  for (int m = 1; m < 64; m <<= 1) v2 += __shfl_xor(v2, m);
  if ((t & 63) == 0) sred[t >> 6] = v2;
  __syncthreads();
  if (t == 0) out[g] = sred[0] + sred[1] + bout[0];
}

extern "C" void kernel_launch(void* const* d_in, const int* in_sizes, int n_in,
                              void* d_out, int out_size, void* d_ws, size_t ws_size,
                              hipStream_t stream) {
  const float* x     = (const float*)d_in[0];
  const float* mwt   = (const float*)d_in[1];
  const float* Wc0s  = (const float*)d_in[2];
  const float* Wc0n  = (const float*)d_in[3];
  const float* bc0   = (const float*)d_in[4];
  const float* g0    = (const float*)d_in[5];
  const float* b0    = (const float*)d_in[6];
  const float* m0    = (const float*)d_in[7];
  const float* v0    = (const float*)d_in[8];
  const float* Wc1s  = (const float*)d_in[9];
  const float* Wc1n  = (const float*)d_in[10];
  const float* bc1   = (const float*)d_in[11];
  const float* g1    = (const float*)d_in[12];
  const float* b1    = (const float*)d_in[13];
  const float* m1    = (const float*)d_in[14];
  const float* v1    = (const float*)d_in[15];
  const float* Wa    = (const float*)d_in[16];
  const float* ba    = (const float*)d_in[17];
  const float* Wr0   = (const float*)d_in[18];
  const float* br0   = (const float*)d_in[19];
  const float* Wr1   = (const float*)d_in[20];
  const float* br1   = (const float*)d_in[21];
  const float* Wout  = (const float*)d_in[22];
  const float* bout  = (const float*)d_in[23];
  const int*   ei    = (const int*)d_in[24];

  unsigned short* wbf = (unsigned short*)d_ws;                 // 131072 B
  float* cst    = (float*)((char*)d_ws + 131072);              // 2048 B
  float* wr0t   = (float*)((char*)d_ws + 133120);              // 65536 B
  float* wr1t   = (float*)((char*)d_ws + 198656);              // 65536 B
  float* pooled = (float*)((char*)d_ws + 264192);              // 1048576 B

  prep_kernel<<<dim3(225), dim3(256), 0, stream>>>(Wc0s, Wc0n, Wc1s, Wc1n, Wa,
                                                   bc0, g0, b0, m0, v0,
                                                   bc1, g1, b1, m1, v1,
                                                   Wr0, Wr1, wbf, cst, wr0t, wr1t);
  gnn_fused<<<dim3(2048), dim3(512), 0, stream>>>(x, mwt, ei, wbf, cst, ba, pooled);
  readout_kernel<<<dim3(2048), dim3(128), 0, stream>>>(pooled, wr0t, br0, wr1t, br1,
                                                       Wout, bout, (float*)d_out);
}

// Round 12
// 163.175 us; speedup vs baseline: 1.2573x; 1.2573x over previous
//
#include <hip/hip_runtime.h>

#define N_EDGES_C 1048576

typedef __attribute__((ext_vector_type(8))) __bf16 bf16x8;
typedef __attribute__((ext_vector_type(4))) __bf16 bf16x4;
typedef __attribute__((ext_vector_type(4))) float f32x4;
typedef __attribute__((ext_vector_type(4))) unsigned int u32x4;

#define MFMA16(a,b,c) __builtin_amdgcn_mfma_f32_16x16x32_bf16((a),(b),(c),0,0,0)

// LDS-visible barrier that does NOT drain vmcnt: staged weight-chunk loads stay in flight.
#define BARRIER() do { asm volatile("s_waitcnt lgkmcnt(0)" ::: "memory"); \
                       __builtin_amdgcn_s_barrier(); \
                       asm volatile("" ::: "memory"); } while (0)

__device__ __forceinline__ unsigned short f2bf(float f) {
  unsigned int u = __builtin_bit_cast(unsigned int, f);
  u = (u + 0x7fffu + ((u >> 16) & 1u)) >> 16;
  return (unsigned short)u;
}
__device__ __forceinline__ float bf2f(unsigned short h) {
  unsigned int u = ((unsigned int)h) << 16;
  return __builtin_bit_cast(float, u);
}

// swizzled 128x128 bf16 LDS tile (row stride 256B, byte ^= (row&7)<<4)
__device__ __forceinline__ bf16x8 fragM(const unsigned short* sM, int row, int kb, int lane) {
  int r = row + (lane & 15);
  int cb = (kb + ((lane >> 4) << 3)) * 2;
  return *(const bf16x8*)((const char*)sM + r * 256 + (cb ^ ((r & 7) << 4)));
}
__device__ __forceinline__ void putBf(unsigned short* sM, int r, int c, float v) {
  *(__bf16*)((char*)sM + r * 256 + ((c * 2) ^ ((r & 7) << 4))) = (__bf16)v;
}
// Adj counts: u8 [128][128], row stride 128B, byte col ^= (row&7)<<3 (register-only decode)
__device__ __forceinline__ bf16x8 adjFrag(const unsigned char* sCc, float inv,
                                          int mBase, int kb, int lane) {
  int m = mBase + (lane & 15);
  int c = (kb + ((lane >> 4) << 3)) ^ ((m & 7) << 3);
  const unsigned int* p = (const unsigned int*)(sCc + m * 128 + c);
  unsigned int w0 = p[0], w1 = p[1];
  bf16x8 r;
#pragma unroll
  for (int i = 0; i < 4; i++) {
    r[i]     = (__bf16)((float)((w0 >> (8 * i)) & 0xffu) * inv);
    r[4 + i] = (__bf16)((float)((w1 >> (8 * i)) & 0xffu) * inv);
  }
  return r;
}

// K=32 weight chunk ring buffer: [128 rows][32 k] u16 = 8KB, row 64B.
// phys 16B slot = (ks + r + (r>>2)) & 3  -> conflict-free reads & writes.
__device__ __forceinline__ u32x4 stG32(const unsigned short* src, int KS, int ko, int t) {
  int row = t >> 2, ks = t & 3;
  return *(const u32x4*)(src + row * KS + ko + ks * 8);
}
__device__ __forceinline__ void stW32(unsigned short* buf, int t, u32x4 v) {
  int row = t >> 2, ks = t & 3;
  int slot = (ks + row + (row >> 2)) & 3;
  *(u32x4*)((char*)buf + row * 64 + slot * 16) = v;
}
__device__ __forceinline__ bf16x8 fragW32(const unsigned short* buf, int nc, int lane) {
  int r = nc + (lane & 15);
  int ks = lane >> 4;
  int slot = (ks + r + (r >> 2)) & 3;
  return *(const bf16x8*)((const char*)buf + r * 64 + slot * 16);
}

// ---------------- prep: bf16-transpose weights + fold BN + transpose readout W ----------------
__global__ void prep_kernel(const float* __restrict__ Wc0s, const float* __restrict__ Wc0n,
                            const float* __restrict__ Wc1s, const float* __restrict__ Wc1n,
                            const float* __restrict__ Wa,
                            const float* __restrict__ bc0, const float* __restrict__ g0,
                            const float* __restrict__ b0, const float* __restrict__ m0,
                            const float* __restrict__ v0,
                            const float* __restrict__ bc1, const float* __restrict__ g1,
                            const float* __restrict__ b1, const float* __restrict__ m1,
                            const float* __restrict__ v1,
                            const float* __restrict__ Wr0, const float* __restrict__ Wr1,
                            unsigned short* __restrict__ wbf, float* __restrict__ cst,
                            float* __restrict__ wr0t, float* __restrict__ wr1t) {
  int t = blockIdx.x * blockDim.x + threadIdx.x;
  if (t < 8192) {                       // 64x128 -> [d][f]
    int d = t >> 6, f = t & 63;
    wbf[t]        = f2bf(Wc0s[f * 128 + d]);
    wbf[8192 + t] = f2bf(Wc0n[f * 128 + d]);
  } else if (t < 24576) {               // 128x128 -> [d][k]
    int i = t - 8192;
    int d = i >> 7, k = i & 127;
    wbf[16384 + i] = f2bf(Wc1s[k * 128 + d]);
    wbf[32768 + i] = f2bf(Wc1n[k * 128 + d]);
    wbf[49152 + i] = f2bf(Wa[k * 128 + d]);
  } else if (t < 24704) {
    int d = t - 24576;
    float s0 = g0[d] * rsqrtf(v0[d] + 1e-5f);
    cst[d]       = s0;
    cst[128 + d] = (bc0[d] - m0[d]) * s0 + b0[d];
    float s1 = g1[d] * rsqrtf(v1[d] + 1e-5f);
    cst[256 + d] = s1;
    cst[384 + d] = (bc1[d] - m1[d]) * s1 + b1[d];
  } else if (t < 57472) {               // readout weights f32 transpose
    int i = t - 24704;
    int which = i >> 14;
    int k = i & 16383;
    int d = k >> 7, j = k & 127;
    float v = (which ? Wr1 : Wr0)[j * 128 + d];
    (which ? wr1t : wr0t)[k] = v;
  }
}

// ---------------- fused per-graph kernel: 1 block = 1 graph, ~75KB LDS, 2 blocks/CU ----------------
__global__ __launch_bounds__(512, 4)
void gnn_fused(const float* __restrict__ x, const float* __restrict__ mwt,
               const int* __restrict__ ei,
               const unsigned short* __restrict__ wbf, const float* __restrict__ cst,
               const float* __restrict__ ba,
               float* __restrict__ pooled) {
  __shared__ unsigned short sM[128 * 128];   // 32KB: x / V^T / h / p (swizzled)
  __shared__ unsigned char  sC[128 * 128];   // 16KB: Adj u8 counts
  __shared__ unsigned short sW[3][4096];     // 3 x 8KB weight chunk ring
  __shared__ float sDeg[128];
  __shared__ float sPool[128];
  __shared__ float sV1[128];                 // rowsum[0:64] / colsum[64:128]

  const int gb = blockIdx.x;
  const int t = threadIdx.x;
  const int lane = t & 63;
  const int w = t >> 6;              // wave 0..7
  const int col = lane & 15;
  const int r0 = (lane >> 4) << 2;
  const f32x4 zero = {0.f, 0.f, 0.f, 0.f};
  u32x4 st0, st1;                    // in-flight stage regs

  // ---- Ph0: issue c0,c1,c2 + edge loads; zero; x -> sM
  st0 = stG32(wbf + 8192, 64, 0, t);   // c0 = W0n k0-31
  st1 = stG32(wbf + 8192, 64, 32, t);  // c1 = W0n k32-63
  u32x4 st2 = stG32(wbf, 64, 0, t);    // c2 = W0s k0-31
  int els, eld;
  {
    int e = gb * 512 + t;
    els = ei[e] & 127;
    eld = ei[N_EDGES_C + e] & 127;
  }
  {
    unsigned int* c32 = (unsigned int*)sC;
    for (int i = t; i < 4096; i += 512) c32[i] = 0u;
    if (t < 128) { sPool[t] = 0.f; sV1[t] = 0.f; sDeg[t] = 0.f; }
  }
  {
    const float4* xg = (const float4*)(x + (size_t)gb * 8192);
#pragma unroll
    for (int i = 0; i < 4; i++) {
      int vi = t + i * 512;
      float4 v = xg[vi];
      int node = vi >> 4;
      int f = (vi & 15) * 4;
      bf16x4 q = {(__bf16)v.x, (__bf16)v.y, (__bf16)v.z, (__bf16)v.w};
      *(bf16x4*)((char*)sM + node * 256 + ((f * 2) ^ ((node & 7) << 4))) = q;
    }
  }
  BARRIER();

  // ---- Ph1: hist + deg; commit c0,c1,c2; xA preload
  {
    int cb = els ^ ((eld & 7) << 3);
    int idx = eld * 128 + cb;
    atomicAdd((unsigned int*)(sC + (idx & ~3)), 1u << ((idx & 3) * 8));
    atomicAdd(&sDeg[eld], 1.f);
  }
  stW32(sW[0], t, st0);
  stW32(sW[1], t, st1);
  stW32(sW[2], t, st2);
  bf16x8 xA0 = fragM(sM, w * 16, 0, lane);
  bf16x8 xA1 = fragM(sM, w * 16, 32, lane);
  BARRIER();

  f32x4 acc[8];

  // ---- Ph2: issue c3,c4; V0 = xA0@c0 + xA1@c1; write V0^T
  st0 = stG32(wbf, 64, 32, t);           // c3 = W0s k32-63 -> ring0
  st1 = stG32(wbf + 32768, 128, 0, t);   // c4 = W1n k0 -> ring1
#pragma unroll
  for (int n = 0; n < 8; n++) acc[n] = zero;
#pragma unroll
  for (int n = 0; n < 8; n++) acc[n] = MFMA16(xA0, fragW32(sW[0], n * 16, lane), acc[n]);
#pragma unroll
  for (int n = 0; n < 8; n++) acc[n] = MFMA16(xA1, fragW32(sW[1], n * 16, lane), acc[n]);
#pragma unroll
  for (int n = 0; n < 8; n++) {  // V0^T[d][node]
    bf16x4 q = {(__bf16)acc[n][0], (__bf16)acc[n][1], (__bf16)acc[n][2], (__bf16)acc[n][3]};
    int d = n * 16 + col;
    *(bf16x4*)((char*)sM + d * 256 + (((w * 16 + r0) * 2) ^ ((d & 7) << 4))) = q;
  }
  BARRIER();

  // ---- Ph3: commit c3,c4; issue c5; acc = Adj@V0 + xA0@c2
  stW32(sW[0], t, st0);
  stW32(sW[1], t, st1);
  st0 = stG32(wbf + 32768, 128, 32, t);  // c5 = W1n k32 -> ring2
  const float invRow = 1.f / fmaxf(sDeg[w * 16 + col], 1.f);
#pragma unroll
  for (int n = 0; n < 8; n++) acc[n] = zero;
#pragma unroll
  for (int n = 0; n < 8; n++) acc[n] = MFMA16(xA0, fragW32(sW[2], n * 16, lane), acc[n]);
  for (int kb = 0; kb < 4; kb++) {
    bf16x8 aF = adjFrag(sC, invRow, w * 16, kb * 32, lane);
#pragma unroll
    for (int n = 0; n < 8; n++)
      acc[n] = MFMA16(aF, fragM(sM, n * 16, kb * 32, lane), acc[n]);
  }
  BARRIER();

  // ---- Ph4: commit c5; issue c6; acc += xA1@c3; BN0 epi -> h1; hA preload
  stW32(sW[2], t, st0);
  st1 = stG32(wbf + 32768, 128, 64, t);  // c6 = W1n k64 -> ring0
#pragma unroll
  for (int n = 0; n < 8; n++) acc[n] = MFMA16(xA1, fragW32(sW[0], n * 16, lane), acc[n]);
#pragma unroll
  for (int n = 0; n < 8; n++) {
    int d = n * 16 + col;
    float mul = cst[d], add = cst[128 + d];
#pragma unroll
    for (int r = 0; r < 4; r++) {
      float v = acc[n][r] * mul + add;
      v = v > 0.f ? v : 0.01f * v;
      putBf(sM, w * 16 + r0 + r, d, v);
    }
  }
  bf16x8 hA0 = fragM(sM, w * 16, 0, lane);   // own rows: same-wave RAW ok
  bf16x8 hA1 = fragM(sM, w * 16, 32, lane);
  bf16x8 hA2 = fragM(sM, w * 16, 64, lane);
  bf16x8 hA3 = fragM(sM, w * 16, 96, lane);
  BARRIER();

  // ---- Ph5: commit c6; issue c7; accV = hA0@c4
  stW32(sW[0], t, st1);
  st0 = stG32(wbf + 32768, 128, 96, t);  // c7 = W1n k96 -> ring1
#pragma unroll
  for (int n = 0; n < 8; n++) acc[n] = zero;
#pragma unroll
  for (int n = 0; n < 8; n++) acc[n] = MFMA16(hA0, fragW32(sW[1], n * 16, lane), acc[n]);
  BARRIER();

  // ---- Ph6: commit c7; issue c8; accV += hA1@c5
  stW32(sW[1], t, st0);
  st1 = stG32(wbf + 16384, 128, 0, t);   // c8 = W1s k0 -> ring2
#pragma unroll
  for (int n = 0; n < 8; n++) acc[n] = MFMA16(hA1, fragW32(sW[2], n * 16, lane), acc[n]);
  BARRIER();

  // ---- Ph7: commit c8; issue c9; accV += hA2@c6
  stW32(sW[2], t, st1);
  st0 = stG32(wbf + 16384, 128, 32, t);  // c9 = W1s k32 -> ring0
#pragma unroll
  for (int n = 0; n < 8; n++) acc[n] = MFMA16(hA2, fragW32(sW[0], n * 16, lane), acc[n]);
  BARRIER();

  // ---- Ph8: commit c9; issue c10; accV += hA3@c7; write V1^T
  stW32(sW[0], t, st0);
  st1 = stG32(wbf + 16384, 128, 64, t);  // c10 = W1s k64 -> ring1
#pragma unroll
  for (int n = 0; n < 8; n++) acc[n] = MFMA16(hA3, fragW32(sW[1], n * 16, lane), acc[n]);
#pragma unroll
  for (int n = 0; n < 8; n++) {
    bf16x4 q = {(__bf16)acc[n][0], (__bf16)acc[n][1], (__bf16)acc[n][2], (__bf16)acc[n][3]};
    int d = n * 16 + col;
    *(bf16x4*)((char*)sM + d * 256 + (((w * 16 + r0) * 2) ^ ((d & 7) << 4))) = q;
  }
  BARRIER();

  // ---- Ph9: commit c10; issue c11; acc = Adj@V1
  stW32(sW[1], t, st1);
  st0 = stG32(wbf + 16384, 128, 96, t);  // c11 = W1s k96 -> ring2
#pragma unroll
  for (int n = 0; n < 8; n++) acc[n] = zero;
  for (int kb = 0; kb < 4; kb++) {
    bf16x8 aF = adjFrag(sC, invRow, w * 16, kb * 32, lane);
#pragma unroll
    for (int n = 0; n < 8; n++)
      acc[n] = MFMA16(aF, fragM(sM, n * 16, kb * 32, lane), acc[n]);
  }
  BARRIER();

  // ---- Ph10: issue c12; acc += hA0@c8   (no commit: ring2 busy until c8 read)
  st1 = stG32(wbf + 49152, 128, 0, t);   // c12 = Wa k0 -> ring0
#pragma unroll
  for (int n = 0; n < 8; n++) acc[n] = MFMA16(hA0, fragW32(sW[2], n * 16, lane), acc[n]);
  BARRIER();

  // ---- Ph11: commit c11; issue c13; acc += hA1@c9; mwr preload
  stW32(sW[2], t, st0);
  st0 = stG32(wbf + 49152, 128, 32, t);  // c13 = Wa k32 -> ring1
  float mwr[4];
#pragma unroll
  for (int r = 0; r < 4; r++) mwr[r] = mwt[(size_t)gb * 128 + w * 16 + r0 + r];
#pragma unroll
  for (int n = 0; n < 8; n++) acc[n] = MFMA16(hA1, fragW32(sW[0], n * 16, lane), acc[n]);
  BARRIER();

  // ---- Ph12: commit c12; issue c14; acc += hA2@c10
  stW32(sW[0], t, st1);
  st1 = stG32(wbf + 49152, 128, 64, t);  // c14 = Wa k64 -> ring2
#pragma unroll
  for (int n = 0; n < 8; n++) acc[n] = MFMA16(hA2, fragW32(sW[1], n * 16, lane), acc[n]);
  BARRIER();

  // ---- Ph13: commit c13; issue c15; acc += hA3@c11; BN1 epi -> h2 + pool; hA reload
  stW32(sW[1], t, st0);
  st0 = stG32(wbf + 49152, 128, 96, t);  // c15 = Wa k96 -> ring0
#pragma unroll
  for (int n = 0; n < 8; n++) acc[n] = MFMA16(hA3, fragW32(sW[2], n * 16, lane), acc[n]);
#pragma unroll
  for (int n = 0; n < 8; n++) {
    int d = n * 16 + col;
    float mul = cst[256 + d], add = cst[384 + d];
    float csum = 0.f;
#pragma unroll
    for (int r = 0; r < 4; r++) {
      float v = acc[n][r] * mul + add;
      v = v > 0.f ? v : 0.01f * v;
      v *= mwr[r];
      putBf(sM, w * 16 + r0 + r, d, v);
      csum += v;
    }
    csum += __shfl_xor(csum, 16);
    csum += __shfl_xor(csum, 32);
    if (lane < 16) atomicAdd(&sPool[d], csum);
  }
  hA0 = fragM(sM, w * 16, 0, lane);    // h2 own rows
  hA1 = fragM(sM, w * 16, 32, lane);
  hA2 = fragM(sM, w * 16, 64, lane);
  hA3 = fragM(sM, w * 16, 96, lane);
  BARRIER();

  // ---- Ph14: commit c14; accP = hA0@c12
  stW32(sW[2], t, st1);
#pragma unroll
  for (int n = 0; n < 8; n++) acc[n] = zero;
#pragma unroll
  for (int n = 0; n < 8; n++) acc[n] = MFMA16(hA0, fragW32(sW[0], n * 16, lane), acc[n]);
  BARRIER();

  // ---- Ph15: commit c15; accP += hA1@c13
  stW32(sW[0], t, st0);
#pragma unroll
  for (int n = 0; n < 8; n++) acc[n] = MFMA16(hA1, fragW32(sW[1], n * 16, lane), acc[n]);
  BARRIER();

  // ---- Ph16: accP += hA2@c14
#pragma unroll
  for (int n = 0; n < 8; n++) acc[n] = MFMA16(hA2, fragW32(sW[2], n * 16, lane), acc[n]);
  BARRIER();

  // ---- Ph17: accP += hA3@c15; +ba leaky -> p own rows
#pragma unroll
  for (int n = 0; n < 8; n++) acc[n] = MFMA16(hA3, fragW32(sW[0], n * 16, lane), acc[n]);
#pragma unroll
  for (int n = 0; n < 8; n++) {
    int d = n * 16 + col;
    float bav = ba[d];
#pragma unroll
    for (int r = 0; r < 4; r++) {
      float v = acc[n][r] + bav;
      v = v > 0.f ? v : 0.01f * v;
      putBf(sM, w * 16 + r0 + r, d, v);
    }
  }
  BARRIER();  // p complete for all rows

  // ---- Ph18: pair tiles -> sigmoid -> row/col sums (pair never stored)
  {
    f32x4 acc2[2] = {zero, zero};
    for (int kb = 0; kb < 128; kb += 32) {
#pragma unroll
      for (int i = 0; i < 2; i++) {
        int T = w * 2 + i;
        bf16x8 a = fragM(sM, (T >> 2) * 16, kb, lane);       // pA rows mb..mb+15
        bf16x8 b = fragM(sM, 64 + (T & 3) * 16, kb, lane);   // pB rows nb..nb+15
        acc2[i] = MFMA16(a, b, acc2[i]);
      }
    }
#pragma unroll
    for (int i = 0; i < 2; i++) {
      int T = w * 2 + i, mb = (T >> 2) * 16, nb = (T & 3) * 16;
      float s0 = 1.f / (1.f + __expf(-acc2[i][0]));
      float s1 = 1.f / (1.f + __expf(-acc2[i][1]));
      float s2 = 1.f / (1.f + __expf(-acc2[i][2]));
      float s3 = 1.f / (1.f + __expf(-acc2[i][3]));
      atomicAdd(&sV1[64 + nb + col], s0 + s1 + s2 + s3);
#pragma unroll
      for (int m = 1; m < 16; m <<= 1) {
        s0 += __shfl_xor(s0, m);
        s1 += __shfl_xor(s1, m);
        s2 += __shfl_xor(s2, m);
        s3 += __shfl_xor(s3, m);
      }
      if (col < 4) {
        float v = col == 0 ? s0 : (col == 1 ? s1 : (col == 2 ? s2 : s3));
        atomicAdd(&sV1[mb + r0 + col], v);
      }
    }
  }
  BARRIER();

  // ---- Ph19: delta pool: sPool[d] += sum_node u[node]*p[node][d]
  {
    int d = t & 127, q = t >> 7;
    float s = 0.f;
#pragma unroll
    for (int i = 0; i < 32; i++) {
      int node = q * 32 + i;
      float u = sV1[node];
      float pv = bf2f(*(const unsigned short*)((const char*)sM + node * 256 +
                                               ((2 * d) ^ ((node & 7) << 4))));
      s += u * pv;
    }
    atomicAdd(&sPool[d], s);
  }
  BARRIER();

  // ---- Ph20: write pooled mean
  if (t < 128) pooled[(size_t)gb * 128 + t] = sPool[t] * (1.f / 128.f);
}

// ---------------- readout: r = leaky(leaky(pooled@Wr0+br0)@Wr1+br1)@Wout + bout ----------------
__global__ __launch_bounds__(128)
void readout_kernel(const float* __restrict__ pooled,
                    const float* __restrict__ wr0t, const float* __restrict__ br0,
                    const float* __restrict__ wr1t, const float* __restrict__ br1,
                    const float* __restrict__ Wout, const float* __restrict__ bout,
                    float* __restrict__ out) {
  __shared__ float pl[128], t1[128];
  __shared__ float sred[2];
  int g = blockIdx.x, t = threadIdx.x;
  pl[t] = pooled[(size_t)g * 128 + t];
  __syncthreads();
  {
    const float* row = wr0t + t * 128;
    float s = 0.f;
#pragma unroll 8
    for (int j = 0; j < 128; j++) s += pl[j] * row[j];
    s += br0[t];
    t1[t] = s > 0.f ? s : 0.01f * s;
  }
  __syncthreads();
  float v2;
  {
    const float* row = wr1t + t * 128;
    float s = 0.f;
#pragma unroll 8
    for (int j = 0; j < 128; j++) s += t1[j] * row[j];
    s += br1[t];
    s = s > 0.f ? s : 0.01f * s;
    v2 = s * Wout[t];
  }
#pragma unroll
  for (int m = 1; m < 64; m <<= 1) v2 += __shfl_xor(v2, m);
  if ((t & 63) == 0) sred[t >> 6] = v2;
  __syncthreads();
  if (t == 0) out[g] = sred[0] + sred[1] + bout[0];
}

extern "C" void kernel_launch(void* const* d_in, const int* in_sizes, int n_in,
                              void* d_out, int out_size, void* d_ws, size_t ws_size,
                              hipStream_t stream) {
  const float* x     = (const float*)d_in[0];
  const float* mwt   = (const float*)d_in[1];
  const float* Wc0s  = (const float*)d_in[2];
  const float* Wc0n  = (const float*)d_in[3];
  const float* bc0   = (const float*)d_in[4];
  const float* g0    = (const float*)d_in[5];
  const float* b0    = (const float*)d_in[6];
  const float* m0    = (const float*)d_in[7];
  const float* v0    = (const float*)d_in[8];
  const float* Wc1s  = (const float*)d_in[9];
  const float* Wc1n  = (const float*)d_in[10];
  const float* bc1   = (const float*)d_in[11];
  const float* g1    = (const float*)d_in[12];
  const float* b1    = (const float*)d_in[13];
  const float* m1    = (const float*)d_in[14];
  const float* v1    = (const float*)d_in[15];
  const float* Wa    = (const float*)d_in[16];
  const float* ba    = (const float*)d_in[17];
  const float* Wr0   = (const float*)d_in[18];
  const float* br0   = (const float*)d_in[19];
  const float* Wr1   = (const float*)d_in[20];
  const float* br1   = (const float*)d_in[21];
  const float* Wout  = (const float*)d_in[22];
  const float* bout  = (const float*)d_in[23];
  const int*   ei    = (const int*)d_in[24];

  unsigned short* wbf = (unsigned short*)d_ws;                 // 131072 B
  float* cst    = (float*)((char*)d_ws + 131072);              // 2048 B
  float* wr0t   = (float*)((char*)d_ws + 133120);              // 65536 B
  float* wr1t   = (float*)((char*)d_ws + 198656);              // 65536 B
  float* pooled = (float*)((char*)d_ws + 264192);              // 1048576 B

  prep_kernel<<<dim3(225), dim3(256), 0, stream>>>(Wc0s, Wc0n, Wc1s, Wc1n, Wa,
                                                   bc0, g0, b0, m0, v0,
                                                   bc1, g1, b1, m1, v1,
                                                   Wr0, Wr1, wbf, cst, wr0t, wr1t);
  gnn_fused<<<dim3(2048), dim3(512), 0, stream>>>(x, mwt, ei, wbf, cst, ba, pooled);
  readout_kernel<<<dim3(2048), dim3(128), 0, stream>>>(pooled, wr0t, br0, wr1t, br1,
                                                       Wout, bout, (float*)d_out);
}